// Round 1
// baseline (233.364 us; speedup 1.0000x reference)
//
#include <hip/hip_runtime.h>
#include <hip/hip_bf16.h>
#include <math.h>

#define NUM_ENTITY 100000
#define NUM_TYPE   5000
#define DIM        128
#define BATCH      512
#define MARGIN     2.0f

#define BT 64    // batch-tile rows per block
#define TT 64    // type-tile cols per block
#define DC 32    // d-chunk staged in LDS per iteration
#define LSTRIDE 36  // padded LDS row stride in floats (= 4 mod 32 banks, 16B aligned)

__global__ __launch_bounds__(256, 8) void l1dist_sigmoid_kernel(
    const float* __restrict__ ent,
    const float* __restrict__ typ,
    const int*   __restrict__ xb,
    float*       __restrict__ out)
{
    __shared__ float eT[BT * LSTRIDE];
    __shared__ float tT[TT * LSTRIDE];

    const int tid = threadIdx.x;
    const int tx  = tid & 15;   // type-dir thread coord
    const int ty  = tid >> 4;   // batch-dir thread coord
    const int b0  = blockIdx.y * BT;
    const int t0  = blockIdx.x * TT;

    float acc[4][4];
#pragma unroll
    for (int i = 0; i < 4; ++i)
#pragma unroll
        for (int j = 0; j < 4; ++j) acc[i][j] = 0.0f;

    // Cooperative staging: 64 rows x 32 floats = 512 float4 per tile;
    // 256 threads -> 2 float4 each per tile per chunk.
    const int f0 = tid;         // float4 index 0..255
    const int f1 = tid + 256;   // 256..511
    const int r0 = f0 >> 3, c0 = (f0 & 7) << 2;   // row, col(floats)
    const int r1 = f1 >> 3, c1 = (f1 & 7) << 2;

    // gather indices (b-tiles divide BATCH exactly; clamp t rows in last tile)
    const int e_row0 = xb[b0 + r0];
    const int e_row1 = xb[b0 + r1];
    const int t_row0 = min(t0 + r0, NUM_TYPE - 1);
    const int t_row1 = min(t0 + r1, NUM_TYPE - 1);

    for (int dc = 0; dc < DIM; dc += DC) {
        __syncthreads();   // protect LDS from previous chunk's readers
        *(float4*)&eT[r0 * LSTRIDE + c0] = *(const float4*)&ent[e_row0 * DIM + dc + c0];
        *(float4*)&eT[r1 * LSTRIDE + c1] = *(const float4*)&ent[e_row1 * DIM + dc + c1];
        *(float4*)&tT[r0 * LSTRIDE + c0] = *(const float4*)&typ[t_row0 * DIM + dc + c0];
        *(float4*)&tT[r1 * LSTRIDE + c1] = *(const float4*)&typ[t_row1 * DIM + dc + c1];
        __syncthreads();

#pragma unroll
        for (int k = 0; k < DC; k += 4) {
            float4 ev[4], tv[4];
#pragma unroll
            for (int i = 0; i < 4; ++i)
                ev[i] = *(const float4*)&eT[(ty + 16 * i) * LSTRIDE + k];
#pragma unroll
            for (int j = 0; j < 4; ++j)
                tv[j] = *(const float4*)&tT[(tx + 16 * j) * LSTRIDE + k];
#pragma unroll
            for (int i = 0; i < 4; ++i)
#pragma unroll
                for (int j = 0; j < 4; ++j) {
                    acc[i][j] += fabsf(ev[i].x - tv[j].x);
                    acc[i][j] += fabsf(ev[i].y - tv[j].y);
                    acc[i][j] += fabsf(ev[i].z - tv[j].z);
                    acc[i][j] += fabsf(ev[i].w - tv[j].w);
                }
        }
    }

    // epilogue: sigmoid(MARGIN - dist), guarded store on t
#pragma unroll
    for (int i = 0; i < 4; ++i) {
        const int b = b0 + ty + 16 * i;
#pragma unroll
        for (int j = 0; j < 4; ++j) {
            const int t = t0 + tx + 16 * j;
            if (t < NUM_TYPE) {
                const float x = MARGIN - acc[i][j];
                out[b * NUM_TYPE + t] = 1.0f / (1.0f + __expf(-x));
            }
        }
    }
}

extern "C" void kernel_launch(void* const* d_in, const int* in_sizes, int n_in,
                              void* d_out, int out_size, void* d_ws, size_t ws_size,
                              hipStream_t stream) {
    const float* ent = (const float*)d_in[0];
    const float* typ = (const float*)d_in[1];
    const int*   xb  = (const int*)d_in[2];
    float*       out = (float*)d_out;

    dim3 grid((NUM_TYPE + TT - 1) / TT, BATCH / BT);  // (79, 8)
    dim3 block(256);
    l1dist_sigmoid_kernel<<<grid, block, 0, stream>>>(ent, typ, xb, out);
}

// Round 2
// 73.726 us; speedup vs baseline: 3.1653x; 3.1653x over previous
//
#include <hip/hip_runtime.h>
#include <hip/hip_bf16.h>
#include <math.h>

#define NUM_ENTITY 100000
#define NUM_TYPE   5000
#define DIM        128
#define BATCH      512
#define MARGIN     2.0f

#define BT 64    // batch-tile rows per block
#define TT 64    // type-tile cols per block
#define DC 32    // d-chunk staged in LDS per iteration
#define LSTRIDE 36  // padded LDS row stride in floats (= 4 mod 32 banks, 16B aligned)

// (256, 4): 4 waves/EU min -> 128 VGPR budget. Round 1 used (256, 8) -> 64
// VGPR cap -> allocator landed at 32 and spilled acc+operands to scratch
// (~1 GB HBM traffic, 233 us). Inner loop needs ~70-90 live VGPRs.
__global__ __launch_bounds__(256, 4) void l1dist_sigmoid_kernel(
    const float* __restrict__ ent,
    const float* __restrict__ typ,
    const int*   __restrict__ xb,
    float*       __restrict__ out)
{
    __shared__ float eT[BT * LSTRIDE];
    __shared__ float tT[TT * LSTRIDE];

    const int tid = threadIdx.x;
    const int tx  = tid & 15;   // type-dir thread coord
    const int ty  = tid >> 4;   // batch-dir thread coord
    const int b0  = blockIdx.y * BT;
    const int t0  = blockIdx.x * TT;

    float acc[4][4];
#pragma unroll
    for (int i = 0; i < 4; ++i)
#pragma unroll
        for (int j = 0; j < 4; ++j) acc[i][j] = 0.0f;

    // Cooperative staging: 64 rows x 32 floats = 512 float4 per tile;
    // 256 threads -> 2 float4 each per tile per chunk.
    const int f0 = tid;         // float4 index 0..255
    const int f1 = tid + 256;   // 256..511
    const int r0 = f0 >> 3, c0 = (f0 & 7) << 2;   // row, col(floats)
    const int r1 = f1 >> 3, c1 = (f1 & 7) << 2;

    // gather indices (b-tiles divide BATCH exactly; clamp t rows in last tile)
    const int e_row0 = xb[b0 + r0];
    const int e_row1 = xb[b0 + r1];
    const int t_row0 = min(t0 + r0, NUM_TYPE - 1);
    const int t_row1 = min(t0 + r1, NUM_TYPE - 1);

    for (int dc = 0; dc < DIM; dc += DC) {
        __syncthreads();   // protect LDS from previous chunk's readers
        *(float4*)&eT[r0 * LSTRIDE + c0] = *(const float4*)&ent[e_row0 * DIM + dc + c0];
        *(float4*)&eT[r1 * LSTRIDE + c1] = *(const float4*)&ent[e_row1 * DIM + dc + c1];
        *(float4*)&tT[r0 * LSTRIDE + c0] = *(const float4*)&typ[t_row0 * DIM + dc + c0];
        *(float4*)&tT[r1 * LSTRIDE + c1] = *(const float4*)&typ[t_row1 * DIM + dc + c1];
        __syncthreads();

#pragma unroll
        for (int k = 0; k < DC; k += 4) {
            float4 ev[4], tv[4];
#pragma unroll
            for (int i = 0; i < 4; ++i)
                ev[i] = *(const float4*)&eT[(ty + 16 * i) * LSTRIDE + k];
#pragma unroll
            for (int j = 0; j < 4; ++j)
                tv[j] = *(const float4*)&tT[(tx + 16 * j) * LSTRIDE + k];
#pragma unroll
            for (int i = 0; i < 4; ++i)
#pragma unroll
                for (int j = 0; j < 4; ++j) {
                    acc[i][j] += fabsf(ev[i].x - tv[j].x);
                    acc[i][j] += fabsf(ev[i].y - tv[j].y);
                    acc[i][j] += fabsf(ev[i].z - tv[j].z);
                    acc[i][j] += fabsf(ev[i].w - tv[j].w);
                }
        }
    }

    // epilogue: sigmoid(MARGIN - dist), guarded store on t
#pragma unroll
    for (int i = 0; i < 4; ++i) {
        const int b = b0 + ty + 16 * i;
#pragma unroll
        for (int j = 0; j < 4; ++j) {
            const int t = t0 + tx + 16 * j;
            if (t < NUM_TYPE) {
                const float x = MARGIN - acc[i][j];
                out[b * NUM_TYPE + t] = 1.0f / (1.0f + __expf(-x));
            }
        }
    }
}

extern "C" void kernel_launch(void* const* d_in, const int* in_sizes, int n_in,
                              void* d_out, int out_size, void* d_ws, size_t ws_size,
                              hipStream_t stream) {
    const float* ent = (const float*)d_in[0];
    const float* typ = (const float*)d_in[1];
    const int*   xb  = (const int*)d_in[2];
    float*       out = (float*)d_out;

    dim3 grid((NUM_TYPE + TT - 1) / TT, BATCH / BT);  // (79, 8)
    dim3 block(256);
    l1dist_sigmoid_kernel<<<grid, block, 0, stream>>>(ent, typ, xb, out);
}

// Round 3
// 43.407 us; speedup vs baseline: 5.3763x; 1.6985x over previous
//
#include <hip/hip_runtime.h>
#include <hip/hip_bf16.h>
#include <math.h>

#define NUM_ENTITY 100000
#define NUM_TYPE   5000
#define DIM        128
#define BATCH      512
#define MARGIN     2.0f

#define BT 64    // batch-tile rows per block
#define TT 64    // type-tile cols per block
#define DC 32    // d-chunk staged in LDS per iteration
#define LSTRIDE 36  // padded LDS row stride in floats (= 4 mod 32 banks, 16B aligned)

// (256, 1): grid is only 632 blocks (~2.5 blocks/CU), so occupancy caps buy
// nothing. Rounds 1-2 proved launch_bounds-driven VGPR caps (32/64) spill the
// accumulator to scratch: r1 ~1GB HBM scratch traffic @233us, r2 ~230MB @74us.
// Inner loop wants ~60-100 live VGPRs; give the allocator the full 256 budget.
__global__ __launch_bounds__(256, 1) void l1dist_sigmoid_kernel(
    const float* __restrict__ ent,
    const float* __restrict__ typ,
    const int*   __restrict__ xb,
    float*       __restrict__ out)
{
    __shared__ float eT[BT * LSTRIDE];
    __shared__ float tT[TT * LSTRIDE];

    const int tid = threadIdx.x;
    const int tx  = tid & 15;   // type-dir thread coord
    const int ty  = tid >> 4;   // batch-dir thread coord
    const int b0  = blockIdx.y * BT;
    const int t0  = blockIdx.x * TT;

    float acc[4][4];
#pragma unroll
    for (int i = 0; i < 4; ++i)
#pragma unroll
        for (int j = 0; j < 4; ++j) acc[i][j] = 0.0f;

    // Cooperative staging: 64 rows x 32 floats = 512 float4 per tile;
    // 256 threads -> 2 float4 each per tile per chunk.
    const int f0 = tid;         // float4 index 0..255
    const int f1 = tid + 256;   // 256..511
    const int r0 = f0 >> 3, c0 = (f0 & 7) << 2;   // row, col(floats)
    const int r1 = f1 >> 3, c1 = (f1 & 7) << 2;

    // gather indices (b-tiles divide BATCH exactly; clamp t rows in last tile)
    const int e_row0 = xb[b0 + r0];
    const int e_row1 = xb[b0 + r1];
    const int t_row0 = min(t0 + r0, NUM_TYPE - 1);
    const int t_row1 = min(t0 + r1, NUM_TYPE - 1);

    for (int dc = 0; dc < DIM; dc += DC) {
        __syncthreads();   // protect LDS from previous chunk's readers
        *(float4*)&eT[r0 * LSTRIDE + c0] = *(const float4*)&ent[e_row0 * DIM + dc + c0];
        *(float4*)&eT[r1 * LSTRIDE + c1] = *(const float4*)&ent[e_row1 * DIM + dc + c1];
        *(float4*)&tT[r0 * LSTRIDE + c0] = *(const float4*)&typ[t_row0 * DIM + dc + c0];
        *(float4*)&tT[r1 * LSTRIDE + c1] = *(const float4*)&typ[t_row1 * DIM + dc + c1];
        __syncthreads();

#pragma unroll
        for (int k = 0; k < DC; k += 4) {
            float4 ev[4], tv[4];
#pragma unroll
            for (int i = 0; i < 4; ++i)
                ev[i] = *(const float4*)&eT[(ty + 16 * i) * LSTRIDE + k];
#pragma unroll
            for (int j = 0; j < 4; ++j)
                tv[j] = *(const float4*)&tT[(tx + 16 * j) * LSTRIDE + k];
#pragma unroll
            for (int i = 0; i < 4; ++i)
#pragma unroll
                for (int j = 0; j < 4; ++j) {
                    acc[i][j] += fabsf(ev[i].x - tv[j].x);
                    acc[i][j] += fabsf(ev[i].y - tv[j].y);
                    acc[i][j] += fabsf(ev[i].z - tv[j].z);
                    acc[i][j] += fabsf(ev[i].w - tv[j].w);
                }
        }
    }

    // epilogue: sigmoid(MARGIN - dist), guarded store on t
#pragma unroll
    for (int i = 0; i < 4; ++i) {
        const int b = b0 + ty + 16 * i;
#pragma unroll
        for (int j = 0; j < 4; ++j) {
            const int t = t0 + tx + 16 * j;
            if (t < NUM_TYPE) {
                const float x = MARGIN - acc[i][j];
                out[b * NUM_TYPE + t] = 1.0f / (1.0f + __expf(-x));
            }
        }
    }
}

extern "C" void kernel_launch(void* const* d_in, const int* in_sizes, int n_in,
                              void* d_out, int out_size, void* d_ws, size_t ws_size,
                              hipStream_t stream) {
    const float* ent = (const float*)d_in[0];
    const float* typ = (const float*)d_in[1];
    const int*   xb  = (const int*)d_in[2];
    float*       out = (float*)d_out;

    dim3 grid((NUM_TYPE + TT - 1) / TT, BATCH / BT);  // (79, 8)
    dim3 block(256);
    l1dist_sigmoid_kernel<<<grid, block, 0, stream>>>(ent, typ, xb, out);
}